// Round 7
// baseline (197.809 us; speedup 1.0000x reference)
//
#include <hip/hip_runtime.h>
#include <stdint.h>

#define NPTS   4096
#define NSKIP  16384
#define CCH    256
#define CSK    128
#define DIN    384
#define HDIM   256
#define BIGF   1e10f

typedef unsigned short u16;
typedef __attribute__((ext_vector_type(8))) short short8;
typedef __attribute__((ext_vector_type(4))) float floatx4;

__device__ __forceinline__ u16 f2bf(float f) {
    union { float f; uint32_t u; } c; c.f = f;
    uint32_t u = c.u;
    return (u16)((u + 0x7FFFu + ((u >> 16) & 1u)) >> 16);
}

__device__ __forceinline__ double pkkey(float d, int j) {
    return __hiloint2double(__float_as_int(d), j);
}

// ---------------------------------------------------------------------------
// prep+knn merged (identical to R2 best): blocks 0-47 pack W1, 48-79 pack W2
// (ntile-major); blocks 80.. KNN (8 pts/block, 32 threads/pt).
// ---------------------------------------------------------------------------
__global__ __launch_bounds__(256) void prep_knn_kernel(
    const float* __restrict__ W1, const float* __restrict__ W2,
    u16* __restrict__ W1p, u16* __restrict__ W2p,
    const float* __restrict__ pos, const int* __restrict__ batch,
    const float* __restrict__ pos_skip, const int* __restrict__ batch_skip,
    int* __restrict__ idx3, float* __restrict__ w3)
{
    const int bid = blockIdx.x;
    const int t = threadIdx.x;

    if (bid < 80) {
        const float* W = (bid < 48) ? W1 : W2;
        u16* Wp       = (bid < 48) ? W1p : W2p;
        const int KT  = (bid < 48) ? 12 : 8;
        const int g   = ((bid < 48) ? bid : (bid - 48)) * 256 + t;

        const int lane = g & 63;
        const int kt = (g >> 6) % KT;
        const int nt = (g >> 6) / KT;
        const int kbase = kt * 32 + (lane >> 4) * 8;
        const int n = nt * 16 + (lane & 15);
        u16 v[8];
#pragma unroll
        for (int j = 0; j < 8; ++j) v[j] = f2bf(W[(size_t)(kbase + j) * HDIM + n]);
#pragma unroll
        for (int j = 0; j < 8; ++j) Wp[(size_t)g * 8 + j] = v[j];
        return;
    }

    __shared__ int sRange[5];
    if (t < 5) {
        int lo = 0, hi = NPTS;
        while (lo < hi) {
            const int m = (lo + hi) >> 1;
            if (batch[m] < t) lo = m + 1; else hi = m;
        }
        sRange[t] = lo;
    }
    __syncthreads();

    const int i = (bid - 80) * 8 + (t >> 5);
    const int sub = t & 31;
    const int b = batch_skip[i];
    const int start = sRange[b], end = sRange[b + 1];

    const float px = pos_skip[i * 3 + 0];
    const float py = pos_skip[i * 3 + 1];
    const float pz = pos_skip[i * 3 + 2];

    const double BIGKEY = pkkey(BIGF, 0x7FFFFFFF);
    double k0 = BIGKEY, k1 = BIGKEY, k2 = BIGKEY;

    for (int j = start + sub; j < end; j += 32) {
        const float qx = pos[j * 3 + 0];
        const float qy = pos[j * 3 + 1];
        const float qz = pos[j * 3 + 2];
        const float dx = __fsub_rn(px, qx);
        const float dy = __fsub_rn(py, qy);
        const float dz = __fsub_rn(pz, qz);
        const float dd = __fadd_rn(__fadd_rn(__fmul_rn(dx, dx), __fmul_rn(dy, dy)),
                                   __fmul_rn(dz, dz));
        const double kk = pkkey(dd, j);
        const double u0 = fmax(k0, kk); k0 = fmin(k0, kk);
        const double u1 = fmax(k1, u0); k1 = fmin(k1, u0);
        k2 = fmin(k2, u1);
    }

#pragma unroll
    for (int m = 1; m < 32; m <<= 1) {
        const double o0 = __shfl_xor(k0, m);
        const double o1 = __shfl_xor(k1, m);
        const double o2 = __shfl_xor(k2, m);
        double u0 = fmax(k0, o0); k0 = fmin(k0, o0);
        double u1 = fmax(k1, u0); k1 = fmin(k1, u0);
        k2 = fmin(k2, u1);
        u1 = fmax(k1, o1); k1 = fmin(k1, o1);
        k2 = fmin(k2, u1);
        k2 = fmin(k2, o2);
    }

    if (sub == 0) {
        const float d0 = __int_as_float(__double2hiint(k0));
        const float d1 = __int_as_float(__double2hiint(k1));
        const float d2 = __int_as_float(__double2hiint(k2));
        const float w0 = 1.0f / fmaxf(d0, 1e-16f);
        const float w1 = 1.0f / fmaxf(d1, 1e-16f);
        const float w2 = 1.0f / fmaxf(d2, 1e-16f);
        const float inv = 1.0f / (w0 + w1 + w2);
        idx3[i * 3 + 0] = __double2loint(k0);
        idx3[i * 3 + 1] = __double2loint(k1);
        idx3[i * 3 + 2] = __double2loint(k2);
        w3[i * 3 + 0] = w0 * inv; w3[i * 3 + 1] = w1 * inv; w3[i * 3 + 2] = w2 * inv;
    }
}

// ---------------------------------------------------------------------------
// Fused MLP — R13 PROBE: identical R2 body executed 3x (idempotent).
// Opaque-pointer asm per pass defeats cross-pass load CSE; end-of-pass
// barrier protects sA reuse. Purpose: surface this dispatch in rocprof
// top-5 (> 43 us fills) with full counters, and split cold vs warm cost.
// ---------------------------------------------------------------------------
__global__ __launch_bounds__(256) void fused_mlp_kernel(
    const float* __restrict__ x, const float* __restrict__ x_skip,
    const int* __restrict__ idx3, const float* __restrict__ w3,
    const u16* __restrict__ W1p, const float* __restrict__ b1,
    const u16* __restrict__ W2p, const float* __restrict__ b2,
    const float* __restrict__ pos_skip, const int* __restrict__ batch_skip,
    float* __restrict__ out)
{
    __shared__ u16 sA[32 * 392];   // 25088 B; reused as h[32][264]
    const int t = threadIdx.x;
    const int row0 = blockIdx.x * 32;
    const int wave = t >> 6, lane = t & 63;
    const int quad = lane >> 4, ml = lane & 15;

    for (int pass = 0; pass < 3; ++pass) {
        // opaque pointers: compiler must assume they changed -> no cross-pass CSE
        const float* xp  = x;      const float* xsp = x_skip;
        const int*   ip  = idx3;   const float* wp  = w3;
        const u16*   w1p = W1p;    const u16*   w2p = W2p;
        asm volatile("" : "+s"(xp), "+s"(xsp), "+s"(ip), "+s"(wp), "+s"(w1p), "+s"(w2p));

        // --- interp: 32 rows x 64 float4 ---
#pragma unroll
        for (int k = 0; k < 8; ++k) {
            const int g = t + 256 * k;
            const int row = g >> 6, c4 = g & 63;
            const int R = row0 + row;
            const int i0 = ip[R * 3 + 0], i1 = ip[R * 3 + 1], i2 = ip[R * 3 + 2];
            const float w0 = wp[R * 3 + 0], w1 = wp[R * 3 + 1], w2 = wp[R * 3 + 2];
            const float4 v0 = *(const float4*)(xp + (size_t)i0 * CCH + c4 * 4);
            const float4 v1 = *(const float4*)(xp + (size_t)i1 * CCH + c4 * 4);
            const float4 v2 = *(const float4*)(xp + (size_t)i2 * CCH + c4 * 4);
            const float a  = w0 * v0.x + w1 * v1.x + w2 * v2.x;
            const float bq = w0 * v0.y + w1 * v1.y + w2 * v2.y;
            const float cq = w0 * v0.z + w1 * v1.z + w2 * v2.z;
            const float dq = w0 * v0.w + w1 * v1.w + w2 * v2.w;
            uint2 pk;
            pk.x = (uint32_t)f2bf(a)  | ((uint32_t)f2bf(bq) << 16);
            pk.y = (uint32_t)f2bf(cq) | ((uint32_t)f2bf(dq) << 16);
            *(uint2*)(sA + row * 392 + c4 * 4) = pk;
        }
        // --- skip copy: 32 rows x 32 float4 ---
#pragma unroll
        for (int k = 0; k < 4; ++k) {
            const int g = t + 256 * k;
            const int row = g >> 5, c4 = g & 31;
            const float4 v = *(const float4*)(xsp + (size_t)(row0 + row) * CSK + c4 * 4);
            uint2 pk;
            pk.x = (uint32_t)f2bf(v.x) | ((uint32_t)f2bf(v.y) << 16);
            pk.y = (uint32_t)f2bf(v.z) | ((uint32_t)f2bf(v.w) << 16);
            *(uint2*)(sA + row * 392 + CCH + c4 * 4) = pk;
        }
        __syncthreads();

        // --- GEMM1: A[32x384] @ W1 -> h[32x256] ---
        floatx4 acc[2][4] = {};
        {
            const u16* aA = sA + ml * 392 + quad * 8;
            for (int kt = 0; kt < 12; ++kt) {
                short8 a0 = *(const short8*)(aA + kt * 32);
                short8 a1 = *(const short8*)(aA + 16 * 392 + kt * 32);
#pragma unroll
                for (int nt = 0; nt < 4; ++nt) {
                    const int ntile = wave * 4 + nt;
                    short8 bfr = *(const short8*)(w1p + (size_t)((ntile * 12 + kt) * 64 + lane) * 8);
                    acc[0][nt] = __builtin_amdgcn_mfma_f32_16x16x32_bf16(a0, bfr, acc[0][nt], 0, 0, 0);
                    acc[1][nt] = __builtin_amdgcn_mfma_f32_16x16x32_bf16(a1, bfr, acc[1][nt], 0, 0, 0);
                }
            }
        }
        __syncthreads();

        // --- h = relu(acc + b1) -> LDS bf16 [32 x 264] ---
#pragma unroll
        for (int mt = 0; mt < 2; ++mt) {
#pragma unroll
            for (int nt = 0; nt < 4; ++nt) {
                const int n = (wave * 4 + nt) * 16 + ml;
                const float bv = b1[n];
#pragma unroll
                for (int r = 0; r < 4; ++r) {
                    const int m = mt * 16 + quad * 4 + r;
                    sA[m * 264 + n] = f2bf(fmaxf(acc[mt][nt][r] + bv, 0.0f));
                }
            }
        }
        __syncthreads();

        // --- GEMM2: h[32x256] @ W2 -> out (fp32) ---
        floatx4 acc2[2][4] = {};
        {
            const u16* aH = sA + ml * 264 + quad * 8;
            for (int kt = 0; kt < 8; ++kt) {
                short8 a0 = *(const short8*)(aH + kt * 32);
                short8 a1 = *(const short8*)(aH + 16 * 264 + kt * 32);
#pragma unroll
                for (int nt = 0; nt < 4; ++nt) {
                    const int ntile = wave * 4 + nt;
                    short8 bfr = *(const short8*)(w2p + (size_t)((ntile * 8 + kt) * 64 + lane) * 8);
                    acc2[0][nt] = __builtin_amdgcn_mfma_f32_16x16x32_bf16(a0, bfr, acc2[0][nt], 0, 0, 0);
                    acc2[1][nt] = __builtin_amdgcn_mfma_f32_16x16x32_bf16(a1, bfr, acc2[1][nt], 0, 0, 0);
                }
            }
        }

#pragma unroll
        for (int mt = 0; mt < 2; ++mt) {
#pragma unroll
            for (int nt = 0; nt < 4; ++nt) {
                const int n = (wave * 4 + nt) * 16 + ml;
                const float bv = b2[n];
#pragma unroll
                for (int r = 0; r < 4; ++r) {
                    const int m = row0 + mt * 16 + quad * 4 + r;
                    out[(size_t)m * HDIM + n] = fmaxf(acc2[mt][nt][r] + bv, 0.0f);
                }
            }
        }

        // --- tail: 128 flat elems per block ---
        if (t < 128) {
            const int e = blockIdx.x * 128 + t;
            const size_t base = (size_t)NSKIP * HDIM;
            if (e < NSKIP * 3) out[base + e] = pos_skip[e];
            else               out[base + e] = (float)batch_skip[e - NSKIP * 3];
        }
        __syncthreads();   // protect sA before next pass overwrites it
    }
}

extern "C" void kernel_launch(void* const* d_in, const int* in_sizes, int n_in,
                              void* d_out, int out_size, void* d_ws, size_t ws_size,
                              hipStream_t stream) {
    const float* x         = (const float*)d_in[0];
    const float* pos       = (const float*)d_in[1];
    const int*   batch     = (const int*)d_in[2];
    const float* x_skip    = (const float*)d_in[3];
    const float* pos_skip  = (const float*)d_in[4];
    const int*   batch_skip= (const int*)d_in[5];
    const float* W1        = (const float*)d_in[6];
    const float* b1        = (const float*)d_in[7];
    const float* W2        = (const float*)d_in[8];
    const float* b2        = (const float*)d_in[9];
    float* out = (float*)d_out;

    // ws layout:
    char* ws = (char*)d_ws;
    u16*    W1p   = (u16*)ws;                      // 196608 B
    u16*    W2p   = (u16*)(ws + 196608);           // 131072 B
    int*    idx3  = (int*)(ws + 327680);           // 196608 B
    float*  w3    = (float*)(ws + 524288);         // 196608 B

    prep_knn_kernel<<<80 + NSKIP / 8, 256, 0, stream>>>(W1, W2, W1p, W2p,
                                                        pos, batch,
                                                        pos_skip, batch_skip,
                                                        idx3, w3);
    fused_mlp_kernel<<<NSKIP / 32, 256, 0, stream>>>(x, x_skip, idx3, w3,
                                                     W1p, b1, W2p, b2,
                                                     pos_skip, batch_skip, out);
}

// Round 8
// 118.515 us; speedup vs baseline: 1.6691x; 1.6691x over previous
//
#include <hip/hip_runtime.h>
#include <stdint.h>

#define NPTS   4096
#define NSKIP  16384
#define CCH    256
#define CSK    128
#define DIN    384
#define HDIM   256
#define BIGF   1e10f

typedef unsigned short u16;
typedef __attribute__((ext_vector_type(8))) short short8;
typedef __attribute__((ext_vector_type(4))) float floatx4;

__device__ __forceinline__ u16 f2bf(float f) {
    union { float f; uint32_t u; } c; c.f = f;
    uint32_t u = c.u;
    return (u16)((u + 0x7FFFu + ((u >> 16) & 1u)) >> 16);
}

__device__ __forceinline__ double pkkey(float d, int j) {
    return __hiloint2double(__float_as_int(d), j);
}

// ---------------------------------------------------------------------------
// prep+knn merged (identical to R2 best): blocks 0-47 pack W1, 48-79 pack W2
// (ntile-major); blocks 80.. KNN (8 pts/block, 32 threads/pt).
// ---------------------------------------------------------------------------
__global__ __launch_bounds__(256) void prep_knn_kernel(
    const float* __restrict__ W1, const float* __restrict__ W2,
    u16* __restrict__ W1p, u16* __restrict__ W2p,
    const float* __restrict__ pos, const int* __restrict__ batch,
    const float* __restrict__ pos_skip, const int* __restrict__ batch_skip,
    int* __restrict__ idx3, float* __restrict__ w3)
{
    const int bid = blockIdx.x;
    const int t = threadIdx.x;

    if (bid < 80) {
        const float* W = (bid < 48) ? W1 : W2;
        u16* Wp       = (bid < 48) ? W1p : W2p;
        const int KT  = (bid < 48) ? 12 : 8;
        const int g   = ((bid < 48) ? bid : (bid - 48)) * 256 + t;

        const int lane = g & 63;
        const int kt = (g >> 6) % KT;
        const int nt = (g >> 6) / KT;
        const int kbase = kt * 32 + (lane >> 4) * 8;
        const int n = nt * 16 + (lane & 15);
        u16 v[8];
#pragma unroll
        for (int j = 0; j < 8; ++j) v[j] = f2bf(W[(size_t)(kbase + j) * HDIM + n]);
#pragma unroll
        for (int j = 0; j < 8; ++j) Wp[(size_t)g * 8 + j] = v[j];
        return;
    }

    __shared__ int sRange[5];
    if (t < 5) {
        int lo = 0, hi = NPTS;
        while (lo < hi) {
            const int m = (lo + hi) >> 1;
            if (batch[m] < t) lo = m + 1; else hi = m;
        }
        sRange[t] = lo;
    }
    __syncthreads();

    const int i = (bid - 80) * 8 + (t >> 5);
    const int sub = t & 31;
    const int b = batch_skip[i];
    const int start = sRange[b], end = sRange[b + 1];

    const float px = pos_skip[i * 3 + 0];
    const float py = pos_skip[i * 3 + 1];
    const float pz = pos_skip[i * 3 + 2];

    const double BIGKEY = pkkey(BIGF, 0x7FFFFFFF);
    double k0 = BIGKEY, k1 = BIGKEY, k2 = BIGKEY;

    for (int j = start + sub; j < end; j += 32) {
        const float qx = pos[j * 3 + 0];
        const float qy = pos[j * 3 + 1];
        const float qz = pos[j * 3 + 2];
        const float dx = __fsub_rn(px, qx);
        const float dy = __fsub_rn(py, qy);
        const float dz = __fsub_rn(pz, qz);
        const float dd = __fadd_rn(__fadd_rn(__fmul_rn(dx, dx), __fmul_rn(dy, dy)),
                                   __fmul_rn(dz, dz));
        const double kk = pkkey(dd, j);
        const double u0 = fmax(k0, kk); k0 = fmin(k0, kk);
        const double u1 = fmax(k1, u0); k1 = fmin(k1, u0);
        k2 = fmin(k2, u1);
    }

#pragma unroll
    for (int m = 1; m < 32; m <<= 1) {
        const double o0 = __shfl_xor(k0, m);
        const double o1 = __shfl_xor(k1, m);
        const double o2 = __shfl_xor(k2, m);
        double u0 = fmax(k0, o0); k0 = fmin(k0, o0);
        double u1 = fmax(k1, u0); k1 = fmin(k1, u0);
        k2 = fmin(k2, u1);
        u1 = fmax(k1, o1); k1 = fmin(k1, o1);
        k2 = fmin(k2, u1);
        k2 = fmin(k2, o2);
    }

    if (sub == 0) {
        const float d0 = __int_as_float(__double2hiint(k0));
        const float d1 = __int_as_float(__double2hiint(k1));
        const float d2 = __int_as_float(__double2hiint(k2));
        const float w0 = 1.0f / fmaxf(d0, 1e-16f);
        const float w1 = 1.0f / fmaxf(d1, 1e-16f);
        const float w2 = 1.0f / fmaxf(d2, 1e-16f);
        const float inv = 1.0f / (w0 + w1 + w2);
        idx3[i * 3 + 0] = __double2loint(k0);
        idx3[i * 3 + 1] = __double2loint(k1);
        idx3[i * 3 + 2] = __double2loint(k2);
        w3[i * 3 + 0] = w0 * inv; w3[i * 3 + 1] = w1 * inv; w3[i * 3 + 2] = w2 * inv;
    }
}

// ---------------------------------------------------------------------------
// Fused MLP (R14): 32 rows/block, 512 blocks. Latency fixes from R7 probe:
//  (a) kt loops fully unrolled + depth-2 register prefetch of B-fragments
//      (removes loop-carried load->wait->mfma serialization),
//  (b) out written via LDS f32 staging -> contiguous 32KB coalesced stores
//      (full 64B lines, kills the ~17MB/pass RFO FETCH seen in the probe),
//  (c) interp batched 4-wide: all idx/w loads, then all 12 x loads in flight.
// ---------------------------------------------------------------------------
__global__ __launch_bounds__(256) void fused_mlp_kernel(
    const float* __restrict__ x, const float* __restrict__ x_skip,
    const int* __restrict__ idx3, const float* __restrict__ w3,
    const u16* __restrict__ W1p, const float* __restrict__ b1,
    const u16* __restrict__ W2p, const float* __restrict__ b2,
    const float* __restrict__ pos_skip, const int* __restrict__ batch_skip,
    float* __restrict__ out)
{
    __shared__ u16 sA[32 * 392];     // 25088 B; reused as h[32][264]
    __shared__ float sOut[32 * 256]; // 32768 B f32 epilogue staging
    const int t = threadIdx.x;
    const int row0 = blockIdx.x * 32;
    const int wave = t >> 6, lane = t & 63;
    const int quad = lane >> 4, ml = lane & 15;

    // --- interp: 2 half-batches of 4 slots; loads fully batched ---
#pragma unroll
    for (int half = 0; half < 2; ++half) {
        int i0a[4], i1a[4], i2a[4];
        float wa[4], wb[4], wc[4];
#pragma unroll
        for (int k = 0; k < 4; ++k) {
            const int g = t + 256 * (half * 4 + k);
            const int R = row0 + (g >> 6);
            i0a[k] = idx3[R * 3 + 0]; i1a[k] = idx3[R * 3 + 1]; i2a[k] = idx3[R * 3 + 2];
            wa[k] = w3[R * 3 + 0]; wb[k] = w3[R * 3 + 1]; wc[k] = w3[R * 3 + 2];
        }
        float4 v0[4], v1[4], v2[4];
#pragma unroll
        for (int k = 0; k < 4; ++k) {
            const int g = t + 256 * (half * 4 + k);
            const int c4 = g & 63;
            v0[k] = *(const float4*)(x + (size_t)i0a[k] * CCH + c4 * 4);
            v1[k] = *(const float4*)(x + (size_t)i1a[k] * CCH + c4 * 4);
            v2[k] = *(const float4*)(x + (size_t)i2a[k] * CCH + c4 * 4);
        }
#pragma unroll
        for (int k = 0; k < 4; ++k) {
            const int g = t + 256 * (half * 4 + k);
            const int row = g >> 6, c4 = g & 63;
            const float a  = wa[k] * v0[k].x + wb[k] * v1[k].x + wc[k] * v2[k].x;
            const float bq = wa[k] * v0[k].y + wb[k] * v1[k].y + wc[k] * v2[k].y;
            const float cq = wa[k] * v0[k].z + wb[k] * v1[k].z + wc[k] * v2[k].z;
            const float dq = wa[k] * v0[k].w + wb[k] * v1[k].w + wc[k] * v2[k].w;
            uint2 pk;
            pk.x = (uint32_t)f2bf(a)  | ((uint32_t)f2bf(bq) << 16);
            pk.y = (uint32_t)f2bf(cq) | ((uint32_t)f2bf(dq) << 16);
            *(uint2*)(sA + row * 392 + c4 * 4) = pk;
        }
    }
    // --- skip copy: 32 rows x 32 float4 ---
    {
        float4 vs[4];
#pragma unroll
        for (int k = 0; k < 4; ++k) {
            const int g = t + 256 * k;
            const int row = g >> 5, c4 = g & 31;
            vs[k] = *(const float4*)(x_skip + (size_t)(row0 + row) * CSK + c4 * 4);
        }
#pragma unroll
        for (int k = 0; k < 4; ++k) {
            const int g = t + 256 * k;
            const int row = g >> 5, c4 = g & 31;
            uint2 pk;
            pk.x = (uint32_t)f2bf(vs[k].x) | ((uint32_t)f2bf(vs[k].y) << 16);
            pk.y = (uint32_t)f2bf(vs[k].z) | ((uint32_t)f2bf(vs[k].w) << 16);
            *(uint2*)(sA + row * 392 + CCH + c4 * 4) = pk;
        }
    }
    __syncthreads();

    // --- GEMM1: A[32x384] @ W1 -> h[32x256]; depth-2 B prefetch ---
    floatx4 acc[2][4] = {};
    {
        const u16* aA = sA + ml * 392 + quad * 8;
        short8 bbuf[2][4];
#pragma unroll
        for (int nt = 0; nt < 4; ++nt) {
            bbuf[0][nt] = *(const short8*)(W1p + (size_t)(((wave * 4 + nt) * 12 + 0) * 64 + lane) * 8);
            bbuf[1][nt] = *(const short8*)(W1p + (size_t)(((wave * 4 + nt) * 12 + 1) * 64 + lane) * 8);
        }
#pragma unroll
        for (int kt = 0; kt < 12; ++kt) {
            short8 use[4];
#pragma unroll
            for (int nt = 0; nt < 4; ++nt) use[nt] = bbuf[kt & 1][nt];
            if (kt + 2 < 12) {
#pragma unroll
                for (int nt = 0; nt < 4; ++nt)
                    bbuf[kt & 1][nt] = *(const short8*)(W1p + (size_t)(((wave * 4 + nt) * 12 + kt + 2) * 64 + lane) * 8);
            }
            short8 a0 = *(const short8*)(aA + kt * 32);
            short8 a1 = *(const short8*)(aA + 16 * 392 + kt * 32);
#pragma unroll
            for (int nt = 0; nt < 4; ++nt) {
                acc[0][nt] = __builtin_amdgcn_mfma_f32_16x16x32_bf16(a0, use[nt], acc[0][nt], 0, 0, 0);
                acc[1][nt] = __builtin_amdgcn_mfma_f32_16x16x32_bf16(a1, use[nt], acc[1][nt], 0, 0, 0);
            }
        }
    }
    __syncthreads();

    // prefetch GEMM2's first two B-slices under the h-write + barrier
    short8 b2buf[2][4];
#pragma unroll
    for (int nt = 0; nt < 4; ++nt) {
        b2buf[0][nt] = *(const short8*)(W2p + (size_t)(((wave * 4 + nt) * 8 + 0) * 64 + lane) * 8);
        b2buf[1][nt] = *(const short8*)(W2p + (size_t)(((wave * 4 + nt) * 8 + 1) * 64 + lane) * 8);
    }

    // --- h = relu(acc + b1) -> LDS bf16 [32 x 264] ---
#pragma unroll
    for (int mt = 0; mt < 2; ++mt) {
#pragma unroll
        for (int nt = 0; nt < 4; ++nt) {
            const int n = (wave * 4 + nt) * 16 + ml;
            const float bv = b1[n];
#pragma unroll
            for (int r = 0; r < 4; ++r) {
                const int m = mt * 16 + quad * 4 + r;
                sA[m * 264 + n] = f2bf(fmaxf(acc[mt][nt][r] + bv, 0.0f));
            }
        }
    }
    __syncthreads();

    // --- GEMM2: h[32x256] @ W2; depth-2 B prefetch ---
    floatx4 acc2[2][4] = {};
    {
        const u16* aH = sA + ml * 264 + quad * 8;
#pragma unroll
        for (int kt = 0; kt < 8; ++kt) {
            short8 use[4];
#pragma unroll
            for (int nt = 0; nt < 4; ++nt) use[nt] = b2buf[kt & 1][nt];
            if (kt + 2 < 8) {
#pragma unroll
                for (int nt = 0; nt < 4; ++nt)
                    b2buf[kt & 1][nt] = *(const short8*)(W2p + (size_t)(((wave * 4 + nt) * 8 + kt + 2) * 64 + lane) * 8);
            }
            short8 a0 = *(const short8*)(aH + kt * 32);
            short8 a1 = *(const short8*)(aH + 16 * 264 + kt * 32);
#pragma unroll
            for (int nt = 0; nt < 4; ++nt) {
                acc2[0][nt] = __builtin_amdgcn_mfma_f32_16x16x32_bf16(a0, use[nt], acc2[0][nt], 0, 0, 0);
                acc2[1][nt] = __builtin_amdgcn_mfma_f32_16x16x32_bf16(a1, use[nt], acc2[1][nt], 0, 0, 0);
            }
        }
    }

    // --- epilogue: fragments -> sOut (f32) -> coalesced contiguous stores ---
#pragma unroll
    for (int mt = 0; mt < 2; ++mt) {
#pragma unroll
        for (int nt = 0; nt < 4; ++nt) {
            const int n = (wave * 4 + nt) * 16 + ml;
            const float bv = b2[n];
#pragma unroll
            for (int r = 0; r < 4; ++r) {
                const int m = mt * 16 + quad * 4 + r;
                sOut[m * 256 + n] = fmaxf(acc2[mt][nt][r] + bv, 0.0f);
            }
        }
    }
    __syncthreads();
    {
        float* dst = out + (size_t)row0 * HDIM;
#pragma unroll
        for (int k = 0; k < 8; ++k) {
            const int e = t + 256 * k;
            *(float4*)(dst + e * 4) = *(const float4*)(sOut + e * 4);
        }
    }

    // --- tail: 128 flat elems per block ---
    if (t < 128) {
        const int e = blockIdx.x * 128 + t;
        const size_t base = (size_t)NSKIP * HDIM;
        if (e < NSKIP * 3) out[base + e] = pos_skip[e];
        else               out[base + e] = (float)batch_skip[e - NSKIP * 3];
    }
}

extern "C" void kernel_launch(void* const* d_in, const int* in_sizes, int n_in,
                              void* d_out, int out_size, void* d_ws, size_t ws_size,
                              hipStream_t stream) {
    const float* x         = (const float*)d_in[0];
    const float* pos       = (const float*)d_in[1];
    const int*   batch     = (const int*)d_in[2];
    const float* x_skip    = (const float*)d_in[3];
    const float* pos_skip  = (const float*)d_in[4];
    const int*   batch_skip= (const int*)d_in[5];
    const float* W1        = (const float*)d_in[6];
    const float* b1        = (const float*)d_in[7];
    const float* W2        = (const float*)d_in[8];
    const float* b2        = (const float*)d_in[9];
    float* out = (float*)d_out;

    // ws layout:
    char* ws = (char*)d_ws;
    u16*    W1p   = (u16*)ws;                      // 196608 B
    u16*    W2p   = (u16*)(ws + 196608);           // 131072 B
    int*    idx3  = (int*)(ws + 327680);           // 196608 B
    float*  w3    = (float*)(ws + 524288);         // 196608 B

    prep_knn_kernel<<<80 + NSKIP / 8, 256, 0, stream>>>(W1, W2, W1p, W2p,
                                                        pos, batch,
                                                        pos_skip, batch_skip,
                                                        idx3, w3);
    fused_mlp_kernel<<<NSKIP / 32, 256, 0, stream>>>(x, x_skip, idx3, w3,
                                                     W1p, b1, W2p, b2,
                                                     pos_skip, batch_skip, out);
}

// Round 9
// 114.386 us; speedup vs baseline: 1.7293x; 1.0361x over previous
//
#include <hip/hip_runtime.h>
#include <stdint.h>

#define NPTS   4096
#define NSKIP  16384
#define CCH    256
#define CSK    128
#define DIN    384
#define HDIM   256
#define BIGF   1e10f

typedef unsigned short u16;
typedef __attribute__((ext_vector_type(8))) short short8;
typedef __attribute__((ext_vector_type(4))) float floatx4;

__device__ __forceinline__ u16 f2bf(float f) {
    union { float f; uint32_t u; } c; c.f = f;
    uint32_t u = c.u;
    return (u16)((u + 0x7FFFu + ((u >> 16) & 1u)) >> 16);
}

__device__ __forceinline__ double pkkey(float d, int j) {
    return __hiloint2double(__float_as_int(d), j);
}

// ---------------------------------------------------------------------------
// prep+knn merged (identical to R2 best): blocks 0-47 pack W1, 48-79 pack W2
// (ntile-major); blocks 80.. KNN (8 pts/block, 32 threads/pt).
// ---------------------------------------------------------------------------
__global__ __launch_bounds__(256) void prep_knn_kernel(
    const float* __restrict__ W1, const float* __restrict__ W2,
    u16* __restrict__ W1p, u16* __restrict__ W2p,
    const float* __restrict__ pos, const int* __restrict__ batch,
    const float* __restrict__ pos_skip, const int* __restrict__ batch_skip,
    int* __restrict__ idx3, float* __restrict__ w3)
{
    const int bid = blockIdx.x;
    const int t = threadIdx.x;

    if (bid < 80) {
        const float* W = (bid < 48) ? W1 : W2;
        u16* Wp       = (bid < 48) ? W1p : W2p;
        const int KT  = (bid < 48) ? 12 : 8;
        const int g   = ((bid < 48) ? bid : (bid - 48)) * 256 + t;

        const int lane = g & 63;
        const int kt = (g >> 6) % KT;
        const int nt = (g >> 6) / KT;
        const int kbase = kt * 32 + (lane >> 4) * 8;
        const int n = nt * 16 + (lane & 15);
        u16 v[8];
#pragma unroll
        for (int j = 0; j < 8; ++j) v[j] = f2bf(W[(size_t)(kbase + j) * HDIM + n]);
#pragma unroll
        for (int j = 0; j < 8; ++j) Wp[(size_t)g * 8 + j] = v[j];
        return;
    }

    __shared__ int sRange[5];
    if (t < 5) {
        int lo = 0, hi = NPTS;
        while (lo < hi) {
            const int m = (lo + hi) >> 1;
            if (batch[m] < t) lo = m + 1; else hi = m;
        }
        sRange[t] = lo;
    }
    __syncthreads();

    const int i = (bid - 80) * 8 + (t >> 5);
    const int sub = t & 31;
    const int b = batch_skip[i];
    const int start = sRange[b], end = sRange[b + 1];

    const float px = pos_skip[i * 3 + 0];
    const float py = pos_skip[i * 3 + 1];
    const float pz = pos_skip[i * 3 + 2];

    const double BIGKEY = pkkey(BIGF, 0x7FFFFFFF);
    double k0 = BIGKEY, k1 = BIGKEY, k2 = BIGKEY;

    for (int j = start + sub; j < end; j += 32) {
        const float qx = pos[j * 3 + 0];
        const float qy = pos[j * 3 + 1];
        const float qz = pos[j * 3 + 2];
        const float dx = __fsub_rn(px, qx);
        const float dy = __fsub_rn(py, qy);
        const float dz = __fsub_rn(pz, qz);
        const float dd = __fadd_rn(__fadd_rn(__fmul_rn(dx, dx), __fmul_rn(dy, dy)),
                                   __fmul_rn(dz, dz));
        const double kk = pkkey(dd, j);
        const double u0 = fmax(k0, kk); k0 = fmin(k0, kk);
        const double u1 = fmax(k1, u0); k1 = fmin(k1, u0);
        k2 = fmin(k2, u1);
    }

#pragma unroll
    for (int m = 1; m < 32; m <<= 1) {
        const double o0 = __shfl_xor(k0, m);
        const double o1 = __shfl_xor(k1, m);
        const double o2 = __shfl_xor(k2, m);
        double u0 = fmax(k0, o0); k0 = fmin(k0, o0);
        double u1 = fmax(k1, u0); k1 = fmin(k1, u0);
        k2 = fmin(k2, u1);
        u1 = fmax(k1, o1); k1 = fmin(k1, o1);
        k2 = fmin(k2, u1);
        k2 = fmin(k2, o2);
    }

    if (sub == 0) {
        const float d0 = __int_as_float(__double2hiint(k0));
        const float d1 = __int_as_float(__double2hiint(k1));
        const float d2 = __int_as_float(__double2hiint(k2));
        const float w0 = 1.0f / fmaxf(d0, 1e-16f);
        const float w1 = 1.0f / fmaxf(d1, 1e-16f);
        const float w2 = 1.0f / fmaxf(d2, 1e-16f);
        const float inv = 1.0f / (w0 + w1 + w2);
        idx3[i * 3 + 0] = __double2loint(k0);
        idx3[i * 3 + 1] = __double2loint(k1);
        idx3[i * 3 + 2] = __double2loint(k2);
        w3[i * 3 + 0] = w0 * inv; w3[i * 3 + 1] = w1 * inv; w3[i * 3 + 2] = w2 * inv;
    }
}

// ---------------------------------------------------------------------------
// Fused MLP (R15): 32 rows/block, 512 blocks, **512 threads (8 waves)** —
// doubles waves/CU (8 -> 16) at IDENTICAL tile size, per-block traffic and
// MFMA count (each wave computes 2 ntiles instead of 4). Pure TLP probe:
// unconfounded version of R3.
// ---------------------------------------------------------------------------
__global__ __launch_bounds__(512) void fused_mlp_kernel(
    const float* __restrict__ x, const float* __restrict__ x_skip,
    const int* __restrict__ idx3, const float* __restrict__ w3,
    const u16* __restrict__ W1p, const float* __restrict__ b1,
    const u16* __restrict__ W2p, const float* __restrict__ b2,
    const float* __restrict__ pos_skip, const int* __restrict__ batch_skip,
    float* __restrict__ out)
{
    __shared__ u16 sA[32 * 392];     // 25088 B; reused as h[32][264]
    __shared__ float sOut[32 * 256]; // 32768 B f32 epilogue staging
    const int t = threadIdx.x;
    const int row0 = blockIdx.x * 32;
    const int wave = t >> 6, lane = t & 63;
    const int quad = lane >> 4, ml = lane & 15;

    // --- interp: 32 rows x 64 float4; 4 slots/thread, all loads batched ---
    {
        int i0a[4], i1a[4], i2a[4];
        float wa[4], wb[4], wc[4];
#pragma unroll
        for (int k = 0; k < 4; ++k) {
            const int g = t + 512 * k;
            const int R = row0 + (g >> 6);
            i0a[k] = idx3[R * 3 + 0]; i1a[k] = idx3[R * 3 + 1]; i2a[k] = idx3[R * 3 + 2];
            wa[k] = w3[R * 3 + 0]; wb[k] = w3[R * 3 + 1]; wc[k] = w3[R * 3 + 2];
        }
        float4 v0[4], v1[4], v2[4];
#pragma unroll
        for (int k = 0; k < 4; ++k) {
            const int g = t + 512 * k;
            const int c4 = g & 63;
            v0[k] = *(const float4*)(x + (size_t)i0a[k] * CCH + c4 * 4);
            v1[k] = *(const float4*)(x + (size_t)i1a[k] * CCH + c4 * 4);
            v2[k] = *(const float4*)(x + (size_t)i2a[k] * CCH + c4 * 4);
        }
#pragma unroll
        for (int k = 0; k < 4; ++k) {
            const int g = t + 512 * k;
            const int row = g >> 6, c4 = g & 63;
            const float a  = wa[k] * v0[k].x + wb[k] * v1[k].x + wc[k] * v2[k].x;
            const float bq = wa[k] * v0[k].y + wb[k] * v1[k].y + wc[k] * v2[k].y;
            const float cq = wa[k] * v0[k].z + wb[k] * v1[k].z + wc[k] * v2[k].z;
            const float dq = wa[k] * v0[k].w + wb[k] * v1[k].w + wc[k] * v2[k].w;
            uint2 pk;
            pk.x = (uint32_t)f2bf(a)  | ((uint32_t)f2bf(bq) << 16);
            pk.y = (uint32_t)f2bf(cq) | ((uint32_t)f2bf(dq) << 16);
            *(uint2*)(sA + row * 392 + c4 * 4) = pk;
        }
    }
    // --- skip copy: 32 rows x 32 float4; 2 slots/thread ---
    {
        float4 vs[2];
#pragma unroll
        for (int k = 0; k < 2; ++k) {
            const int g = t + 512 * k;
            const int row = g >> 5, c4 = g & 31;
            vs[k] = *(const float4*)(x_skip + (size_t)(row0 + row) * CSK + c4 * 4);
        }
#pragma unroll
        for (int k = 0; k < 2; ++k) {
            const int g = t + 512 * k;
            const int row = g >> 5, c4 = g & 31;
            uint2 pk;
            pk.x = (uint32_t)f2bf(vs[k].x) | ((uint32_t)f2bf(vs[k].y) << 16);
            pk.y = (uint32_t)f2bf(vs[k].z) | ((uint32_t)f2bf(vs[k].w) << 16);
            *(uint2*)(sA + row * 392 + CCH + c4 * 4) = pk;
        }
    }
    __syncthreads();

    // --- GEMM1: A[32x384] @ W1 -> h[32x256]; 2 ntiles per wave ---
    floatx4 acc[2][2] = {};
    {
        const u16* aA = sA + ml * 392 + quad * 8;
        for (int kt = 0; kt < 12; ++kt) {
            short8 a0 = *(const short8*)(aA + kt * 32);
            short8 a1 = *(const short8*)(aA + 16 * 392 + kt * 32);
#pragma unroll
            for (int nt = 0; nt < 2; ++nt) {
                const int ntile = wave * 2 + nt;
                short8 bfr = *(const short8*)(W1p + (size_t)((ntile * 12 + kt) * 64 + lane) * 8);
                acc[0][nt] = __builtin_amdgcn_mfma_f32_16x16x32_bf16(a0, bfr, acc[0][nt], 0, 0, 0);
                acc[1][nt] = __builtin_amdgcn_mfma_f32_16x16x32_bf16(a1, bfr, acc[1][nt], 0, 0, 0);
            }
        }
    }
    __syncthreads();

    // --- h = relu(acc + b1) -> LDS bf16 [32 x 264] ---
#pragma unroll
    for (int mt = 0; mt < 2; ++mt) {
#pragma unroll
        for (int nt = 0; nt < 2; ++nt) {
            const int n = (wave * 2 + nt) * 16 + ml;
            const float bv = b1[n];
#pragma unroll
            for (int r = 0; r < 4; ++r) {
                const int m = mt * 16 + quad * 4 + r;
                sA[m * 264 + n] = f2bf(fmaxf(acc[mt][nt][r] + bv, 0.0f));
            }
        }
    }
    __syncthreads();

    // --- GEMM2: h[32x256] @ W2; 2 ntiles per wave ---
    floatx4 acc2[2][2] = {};
    {
        const u16* aH = sA + ml * 264 + quad * 8;
        for (int kt = 0; kt < 8; ++kt) {
            short8 a0 = *(const short8*)(aH + kt * 32);
            short8 a1 = *(const short8*)(aH + 16 * 264 + kt * 32);
#pragma unroll
            for (int nt = 0; nt < 2; ++nt) {
                const int ntile = wave * 2 + nt;
                short8 bfr = *(const short8*)(W2p + (size_t)((ntile * 8 + kt) * 64 + lane) * 8);
                acc2[0][nt] = __builtin_amdgcn_mfma_f32_16x16x32_bf16(a0, bfr, acc2[0][nt], 0, 0, 0);
                acc2[1][nt] = __builtin_amdgcn_mfma_f32_16x16x32_bf16(a1, bfr, acc2[1][nt], 0, 0, 0);
            }
        }
    }

    // --- epilogue: fragments -> sOut (f32) -> coalesced contiguous stores ---
#pragma unroll
    for (int mt = 0; mt < 2; ++mt) {
#pragma unroll
        for (int nt = 0; nt < 2; ++nt) {
            const int n = (wave * 2 + nt) * 16 + ml;
            const float bv = b2[n];
#pragma unroll
            for (int r = 0; r < 4; ++r) {
                const int m = mt * 16 + quad * 4 + r;
                sOut[m * 256 + n] = fmaxf(acc2[mt][nt][r] + bv, 0.0f);
            }
        }
    }
    __syncthreads();
    {
        float* dst = out + (size_t)row0 * HDIM;
#pragma unroll
        for (int k = 0; k < 4; ++k) {
            const int e = t + 512 * k;
            *(float4*)(dst + e * 4) = *(const float4*)(sOut + e * 4);
        }
    }

    // --- tail: 128 flat elems per block ---
    if (t < 128) {
        const int e = blockIdx.x * 128 + t;
        const size_t base = (size_t)NSKIP * HDIM;
        if (e < NSKIP * 3) out[base + e] = pos_skip[e];
        else               out[base + e] = (float)batch_skip[e - NSKIP * 3];
    }
}

extern "C" void kernel_launch(void* const* d_in, const int* in_sizes, int n_in,
                              void* d_out, int out_size, void* d_ws, size_t ws_size,
                              hipStream_t stream) {
    const float* x         = (const float*)d_in[0];
    const float* pos       = (const float*)d_in[1];
    const int*   batch     = (const int*)d_in[2];
    const float* x_skip    = (const float*)d_in[3];
    const float* pos_skip  = (const float*)d_in[4];
    const int*   batch_skip= (const int*)d_in[5];
    const float* W1        = (const float*)d_in[6];
    const float* b1        = (const float*)d_in[7];
    const float* W2        = (const float*)d_in[8];
    const float* b2        = (const float*)d_in[9];
    float* out = (float*)d_out;

    // ws layout:
    char* ws = (char*)d_ws;
    u16*    W1p   = (u16*)ws;                      // 196608 B
    u16*    W2p   = (u16*)(ws + 196608);           // 131072 B
    int*    idx3  = (int*)(ws + 327680);           // 196608 B
    float*  w3    = (float*)(ws + 524288);         // 196608 B

    prep_knn_kernel<<<80 + NSKIP / 8, 256, 0, stream>>>(W1, W2, W1p, W2p,
                                                        pos, batch,
                                                        pos_skip, batch_skip,
                                                        idx3, w3);
    fused_mlp_kernel<<<NSKIP / 32, 512, 0, stream>>>(x, x_skip, idx3, w3,
                                                     W1p, b1, W2p, b2,
                                                     pos_skip, batch_skip, out);
}

// Round 10
// 114.256 us; speedup vs baseline: 1.7313x; 1.0011x over previous
//
#include <hip/hip_runtime.h>
#include <stdint.h>

#define NPTS   4096
#define NSKIP  16384
#define CCH    256
#define CSK    128
#define DIN    384
#define HDIM   256
#define BIGF   1e10f

typedef unsigned short u16;
typedef __attribute__((ext_vector_type(8))) short short8;
typedef __attribute__((ext_vector_type(4))) float floatx4;

__device__ __forceinline__ u16 f2bf(float f) {
    union { float f; uint32_t u; } c; c.f = f;
    uint32_t u = c.u;
    return (u16)((u + 0x7FFFu + ((u >> 16) & 1u)) >> 16);
}

__device__ __forceinline__ double pkkey(float d, int j) {
    return __hiloint2double(__float_as_int(d), j);
}

// ---------------------------------------------------------------------------
// prep+knn merged (identical to R2 best): blocks 0-47 pack W1, 48-79 pack W2
// (ntile-major); blocks 80.. KNN (8 pts/block, 32 threads/pt).
// ---------------------------------------------------------------------------
__global__ __launch_bounds__(256) void prep_knn_kernel(
    const float* __restrict__ W1, const float* __restrict__ W2,
    u16* __restrict__ W1p, u16* __restrict__ W2p,
    const float* __restrict__ pos, const int* __restrict__ batch,
    const float* __restrict__ pos_skip, const int* __restrict__ batch_skip,
    int* __restrict__ idx3, float* __restrict__ w3)
{
    const int bid = blockIdx.x;
    const int t = threadIdx.x;

    if (bid < 80) {
        const float* W = (bid < 48) ? W1 : W2;
        u16* Wp       = (bid < 48) ? W1p : W2p;
        const int KT  = (bid < 48) ? 12 : 8;
        const int g   = ((bid < 48) ? bid : (bid - 48)) * 256 + t;

        const int lane = g & 63;
        const int kt = (g >> 6) % KT;
        const int nt = (g >> 6) / KT;
        const int kbase = kt * 32 + (lane >> 4) * 8;
        const int n = nt * 16 + (lane & 15);
        u16 v[8];
#pragma unroll
        for (int j = 0; j < 8; ++j) v[j] = f2bf(W[(size_t)(kbase + j) * HDIM + n]);
#pragma unroll
        for (int j = 0; j < 8; ++j) Wp[(size_t)g * 8 + j] = v[j];
        return;
    }

    __shared__ int sRange[5];
    if (t < 5) {
        int lo = 0, hi = NPTS;
        while (lo < hi) {
            const int m = (lo + hi) >> 1;
            if (batch[m] < t) lo = m + 1; else hi = m;
        }
        sRange[t] = lo;
    }
    __syncthreads();

    const int i = (bid - 80) * 8 + (t >> 5);
    const int sub = t & 31;
    const int b = batch_skip[i];
    const int start = sRange[b], end = sRange[b + 1];

    const float px = pos_skip[i * 3 + 0];
    const float py = pos_skip[i * 3 + 1];
    const float pz = pos_skip[i * 3 + 2];

    const double BIGKEY = pkkey(BIGF, 0x7FFFFFFF);
    double k0 = BIGKEY, k1 = BIGKEY, k2 = BIGKEY;

    for (int j = start + sub; j < end; j += 32) {
        const float qx = pos[j * 3 + 0];
        const float qy = pos[j * 3 + 1];
        const float qz = pos[j * 3 + 2];
        const float dx = __fsub_rn(px, qx);
        const float dy = __fsub_rn(py, qy);
        const float dz = __fsub_rn(pz, qz);
        const float dd = __fadd_rn(__fadd_rn(__fmul_rn(dx, dx), __fmul_rn(dy, dy)),
                                   __fmul_rn(dz, dz));
        const double kk = pkkey(dd, j);
        const double u0 = fmax(k0, kk); k0 = fmin(k0, kk);
        const double u1 = fmax(k1, u0); k1 = fmin(k1, u0);
        k2 = fmin(k2, u1);
    }

#pragma unroll
    for (int m = 1; m < 32; m <<= 1) {
        const double o0 = __shfl_xor(k0, m);
        const double o1 = __shfl_xor(k1, m);
        const double o2 = __shfl_xor(k2, m);
        double u0 = fmax(k0, o0); k0 = fmin(k0, o0);
        double u1 = fmax(k1, u0); k1 = fmin(k1, u0);
        k2 = fmin(k2, u1);
        u1 = fmax(k1, o1); k1 = fmin(k1, o1);
        k2 = fmin(k2, u1);
        k2 = fmin(k2, o2);
    }

    if (sub == 0) {
        const float d0 = __int_as_float(__double2hiint(k0));
        const float d1 = __int_as_float(__double2hiint(k1));
        const float d2 = __int_as_float(__double2hiint(k2));
        const float w0 = 1.0f / fmaxf(d0, 1e-16f);
        const float w1 = 1.0f / fmaxf(d1, 1e-16f);
        const float w2 = 1.0f / fmaxf(d2, 1e-16f);
        const float inv = 1.0f / (w0 + w1 + w2);
        idx3[i * 3 + 0] = __double2loint(k0);
        idx3[i * 3 + 1] = __double2loint(k1);
        idx3[i * 3 + 2] = __double2loint(k2);
        w3[i * 3 + 0] = w0 * inv; w3[i * 3 + 1] = w1 * inv; w3[i * 3 + 2] = w2 * inv;
    }
}

// ---------------------------------------------------------------------------
// Fused MLP (R16): 32 rows/block, 512 blocks, **1024 threads (16 waves)**,
// __launch_bounds__(1024, 8) -> VGPR<=64 -> 32 waves/CU (hardware max).
// Same tile, same traffic, same MFMA count as R15 (each wave owns 1 ntile).
// Third octave of the unconfounded TLP ladder (8->16 gave -3.6 us).
// Interp slots processed serially to keep live registers under the cap.
// ---------------------------------------------------------------------------
__global__ __launch_bounds__(1024, 8) void fused_mlp_kernel(
    const float* __restrict__ x, const float* __restrict__ x_skip,
    const int* __restrict__ idx3, const float* __restrict__ w3,
    const u16* __restrict__ W1p, const float* __restrict__ b1,
    const u16* __restrict__ W2p, const float* __restrict__ b2,
    const float* __restrict__ pos_skip, const int* __restrict__ batch_skip,
    float* __restrict__ out)
{
    __shared__ u16 sA[32 * 392];     // 25088 B; reused as h[32][264]
    __shared__ float sOut[32 * 256]; // 32768 B f32 epilogue staging
    const int t = threadIdx.x;
    const int row0 = blockIdx.x * 32;
    const int wave = t >> 6, lane = t & 63;
    const int quad = lane >> 4, ml = lane & 15;

    // --- interp: 32 rows x 64 float4; 2 slots/thread, processed serially ---
#pragma unroll
    for (int k = 0; k < 2; ++k) {
        const int g = t + 1024 * k;
        const int row = g >> 6, c4 = g & 63;
        const int R = row0 + row;
        const int i0 = idx3[R * 3 + 0], i1 = idx3[R * 3 + 1], i2 = idx3[R * 3 + 2];
        const float w0 = w3[R * 3 + 0], w1 = w3[R * 3 + 1], w2 = w3[R * 3 + 2];
        const float4 v0 = *(const float4*)(x + (size_t)i0 * CCH + c4 * 4);
        const float4 v1 = *(const float4*)(x + (size_t)i1 * CCH + c4 * 4);
        const float4 v2 = *(const float4*)(x + (size_t)i2 * CCH + c4 * 4);
        const float a  = w0 * v0.x + w1 * v1.x + w2 * v2.x;
        const float bq = w0 * v0.y + w1 * v1.y + w2 * v2.y;
        const float cq = w0 * v0.z + w1 * v1.z + w2 * v2.z;
        const float dq = w0 * v0.w + w1 * v1.w + w2 * v2.w;
        uint2 pk;
        pk.x = (uint32_t)f2bf(a)  | ((uint32_t)f2bf(bq) << 16);
        pk.y = (uint32_t)f2bf(cq) | ((uint32_t)f2bf(dq) << 16);
        *(uint2*)(sA + row * 392 + c4 * 4) = pk;
    }
    // --- skip copy: 32 rows x 32 float4; 1 slot/thread ---
    {
        const int row = t >> 5, c4 = t & 31;
        const float4 v = *(const float4*)(x_skip + (size_t)(row0 + row) * CSK + c4 * 4);
        uint2 pk;
        pk.x = (uint32_t)f2bf(v.x) | ((uint32_t)f2bf(v.y) << 16);
        pk.y = (uint32_t)f2bf(v.z) | ((uint32_t)f2bf(v.w) << 16);
        *(uint2*)(sA + row * 392 + CCH + c4 * 4) = pk;
    }
    __syncthreads();

    // --- GEMM1: A[32x384] @ W1 -> h[32x256]; 1 ntile per wave ---
    floatx4 acc[2] = {};
    {
        const u16* aA = sA + ml * 392 + quad * 8;
        for (int kt = 0; kt < 12; ++kt) {
            short8 a0 = *(const short8*)(aA + kt * 32);
            short8 a1 = *(const short8*)(aA + 16 * 392 + kt * 32);
            short8 bfr = *(const short8*)(W1p + (size_t)((wave * 12 + kt) * 64 + lane) * 8);
            acc[0] = __builtin_amdgcn_mfma_f32_16x16x32_bf16(a0, bfr, acc[0], 0, 0, 0);
            acc[1] = __builtin_amdgcn_mfma_f32_16x16x32_bf16(a1, bfr, acc[1], 0, 0, 0);
        }
    }
    __syncthreads();

    // --- h = relu(acc + b1) -> LDS bf16 [32 x 264] ---
    {
        const int n = wave * 16 + ml;
        const float bv = b1[n];
#pragma unroll
        for (int mt = 0; mt < 2; ++mt) {
#pragma unroll
            for (int r = 0; r < 4; ++r) {
                const int m = mt * 16 + quad * 4 + r;
                sA[m * 264 + n] = f2bf(fmaxf(acc[mt][r] + bv, 0.0f));
            }
        }
    }
    __syncthreads();

    // --- GEMM2: h[32x256] @ W2; 1 ntile per wave ---
    floatx4 acc2[2] = {};
    {
        const u16* aH = sA + ml * 264 + quad * 8;
        for (int kt = 0; kt < 8; ++kt) {
            short8 a0 = *(const short8*)(aH + kt * 32);
            short8 a1 = *(const short8*)(aH + 16 * 264 + kt * 32);
            short8 bfr = *(const short8*)(W2p + (size_t)((wave * 8 + kt) * 64 + lane) * 8);
            acc2[0] = __builtin_amdgcn_mfma_f32_16x16x32_bf16(a0, bfr, acc2[0], 0, 0, 0);
            acc2[1] = __builtin_amdgcn_mfma_f32_16x16x32_bf16(a1, bfr, acc2[1], 0, 0, 0);
        }
    }

    // --- epilogue: fragments -> sOut (f32) -> coalesced contiguous stores ---
    {
        const int n = wave * 16 + ml;
        const float bv = b2[n];
#pragma unroll
        for (int mt = 0; mt < 2; ++mt) {
#pragma unroll
            for (int r = 0; r < 4; ++r) {
                const int m = mt * 16 + quad * 4 + r;
                sOut[m * 256 + n] = fmaxf(acc2[mt][r] + bv, 0.0f);
            }
        }
    }
    __syncthreads();
    {
        float* dst = out + (size_t)row0 * HDIM;
#pragma unroll
        for (int k = 0; k < 2; ++k) {
            const int e = t + 1024 * k;
            *(float4*)(dst + e * 4) = *(const float4*)(sOut + e * 4);
        }
    }

    // --- tail: 128 flat elems per block ---
    if (t < 128) {
        const int e = blockIdx.x * 128 + t;
        const size_t base = (size_t)NSKIP * HDIM;
        if (e < NSKIP * 3) out[base + e] = pos_skip[e];
        else               out[base + e] = (float)batch_skip[e - NSKIP * 3];
    }
}

extern "C" void kernel_launch(void* const* d_in, const int* in_sizes, int n_in,
                              void* d_out, int out_size, void* d_ws, size_t ws_size,
                              hipStream_t stream) {
    const float* x         = (const float*)d_in[0];
    const float* pos       = (const float*)d_in[1];
    const int*   batch     = (const int*)d_in[2];
    const float* x_skip    = (const float*)d_in[3];
    const float* pos_skip  = (const float*)d_in[4];
    const int*   batch_skip= (const int*)d_in[5];
    const float* W1        = (const float*)d_in[6];
    const float* b1        = (const float*)d_in[7];
    const float* W2        = (const float*)d_in[8];
    const float* b2        = (const float*)d_in[9];
    float* out = (float*)d_out;

    // ws layout:
    char* ws = (char*)d_ws;
    u16*    W1p   = (u16*)ws;                      // 196608 B
    u16*    W2p   = (u16*)(ws + 196608);           // 131072 B
    int*    idx3  = (int*)(ws + 327680);           // 196608 B
    float*  w3    = (float*)(ws + 524288);         // 196608 B

    prep_knn_kernel<<<80 + NSKIP / 8, 256, 0, stream>>>(W1, W2, W1p, W2p,
                                                        pos, batch,
                                                        pos_skip, batch_skip,
                                                        idx3, w3);
    fused_mlp_kernel<<<NSKIP / 32, 1024, 0, stream>>>(x, x_skip, idx3, w3,
                                                      W1p, b1, W2p, b2,
                                                      pos_skip, batch_skip, out);
}